// Round 16
// baseline (202.845 us; speedup 1.0000x reference)
//
#include <hip/hip_runtime.h>

#define G 8192
#define IMG_W 512
#define IMG_H 512
#define TILE 16
#define NTX (IMG_W / TILE)  // 32
#define NTY (IMG_H / TILE)  // 32
#define BLK 256
#define BLKB 64             // per-wave chunk staging group
#define CAP 1024            // per-tile list capacity (avg ~190)
#define ALPHA_THRESH (1.0f/255.0f)
#define ALPHA_CAP 0.99f
#define TRANS_THRESH 1e-4f

// -----------------------------------------------------------------------
// Kernel 0: per-gaussian 16x16-tile span (exact conservative cull,
// packed u32) PLUS a packed 64B record per gaussian:
//   f4[0]=(mx,my,0.5a,b)  f4[1]=(0.5c,op,cr,cg)  f4[2]=(cb,0,0,0)
// -----------------------------------------------------------------------
__global__ __launch_bounds__(BLK)
void range_kernel(const float* __restrict__ means2d,
                  const float* __restrict__ conics,
                  const float* __restrict__ colors,
                  const float* __restrict__ opac,
                  unsigned int* __restrict__ ranges,
                  float* __restrict__ tbl)
{
    int g = blockIdx.x * BLK + threadIdx.x;
    if (g >= G) return;
    float op = opac[g];
    float a  = conics[3*g], b = conics[3*g+1], c = conics[3*g+2];
    float mx = means2d[2*g], my = means2d[2*g+1];
    float cr = colors[3*g], cg = colors[3*g+1], cb = colors[3*g+2];

    float4* t4 = (float4*)(tbl + (g << 4));
    t4[0] = make_float4(mx, my, 0.5f * a, b);
    t4[1] = make_float4(0.5f * c, op, cr, cg);
    t4[2] = make_float4(cb, 0.0f, 0.0f, 0.0f);

    unsigned int packed = 0xFFu;          // default: culled
    if (op * 255.0f >= 1.0f) {
        float smax = __logf(op * 255.0f);
        float det = fmaxf(a * c - b * b, 1e-12f);
        float rx = sqrtf(fmaxf(2.0f * smax * c / det, 0.0f)) * 1.0001f + 0.01f;
        float ry = sqrtf(fmaxf(2.0f * smax * a / det, 0.0f)) * 1.0001f + 0.01f;
        int txmin = (int)ceilf ((mx - rx - 15.5f) * 0.0625f);
        int txmax = (int)floorf((mx + rx -  0.5f) * 0.0625f);
        int tymin = (int)ceilf ((my - ry - 15.5f) * 0.0625f);
        int tymax = (int)floorf((my + ry -  0.5f) * 0.0625f);
        if (!(txmax < 0 || txmin > NTX-1 || tymax < 0 || tymin > NTY-1 ||
              txmin > txmax || tymin > tymax)) {
            txmin = max(txmin, 0); txmax = min(txmax, NTX-1);
            tymin = max(tymin, 0); tymax = min(tymax, NTY-1);
            packed = (unsigned)txmin | ((unsigned)txmax << 8)
                   | ((unsigned)tymin << 16) | ((unsigned)tymax << 24);
        }
    }
    ranges[g] = packed;
}

__device__ __forceinline__ int hitp(unsigned p, unsigned btx, unsigned bty)
{
    return (btx >= (p & 0xffu)) & (btx <= ((p >> 8) & 0xffu)) &
           (bty >= ((p >> 16) & 0xffu)) & (bty <= (p >> 24));
}

// -----------------------------------------------------------------------
// Kernel 1 (one 256-thread block per 16x16 tile; 4 waves) — the 86.6us
// R9 kernel with ONE change: LDS footprint 32KB -> 18.5KB by unioning
// the phase-disjoint buffers (fkeys: phase 2 only; sq: phase 3 only;
// part: phase 4 only) in one 16KB buffer, with one extra barrier at the
// sq->part handoff. 8 blocks/CU instead of 4: per-CU work averages over
// 8 tiles (imbalance / sqrt(2)) and 32 waves/CU double latency cover —
// attacking the measured 26% occupancy / end-of-kernel drain directly.
//  Phase 1: barrier-free two-pass scan + ballot compaction (idx order).
//  Phase 2: rank sort, 32-bit float-bit keys, POSITION tiebreak.
//  Phase 3: chunked composite (wave w = depth-chunk w, 4 px/lane),
//           branchless staging rounds (validated verbatim).
//  Phase 4: in-LDS fold C = C0+T0*(C1+T1*(C2+T2*C3)) (validated).
// -----------------------------------------------------------------------
__global__ __launch_bounds__(BLK, 8)
void tile_kernel(const unsigned int* __restrict__ ranges,
                 const float* __restrict__ depths,
                 const float* __restrict__ tbl,
                 float*       __restrict__ out)
{
    __shared__ __align__(16) unsigned short slist[CAP];   // ph 1-3
    __shared__ int woff[4];
    __shared__ __align__(16) unsigned char ubuf[16384];   // ph-disjoint

    unsigned int* fkeys = (unsigned int*)ubuf;            // ph2: 4128 B
    float4 (*sq0)[BLKB] = (float4 (*)[BLKB])ubuf;         // ph3: 4096 B
    float4 (*sq1)[BLKB] = (float4 (*)[BLKB])(ubuf + 4096);//      4096 B
    float  (*sq2)[BLKB] = (float  (*)[BLKB])(ubuf + 8192);//      1024 B
    float4 (*part)[BLK] = (float4 (*)[BLK])ubuf;          // ph4: 16384 B

    const int t = threadIdx.x;
    const int lane = t & 63, w = t >> 6;
    const unsigned btx = blockIdx.x, bty = blockIdx.y;

    // ---- Phase 1, pass A: load + count (no barriers) ----
    const uint4* r4 = (const uint4*)ranges;
    const int wbase = w * (G / 4);            // 2048 gaussians per wave
    uint4 rv[8];
    #pragma unroll
    for (int i = 0; i < 8; ++i)
        rv[i] = r4[(wbase >> 2) + i * 64 + lane];

    int cnt = 0;
    #pragma unroll
    for (int i = 0; i < 8; ++i)
        cnt += hitp(rv[i].x, btx, bty) + hitp(rv[i].y, btx, bty)
             + hitp(rv[i].z, btx, bty) + hitp(rv[i].w, btx, bty);
    #pragma unroll
    for (int d = 1; d < 64; d <<= 1) cnt += __shfl_xor(cnt, d);
    if (lane == 0) woff[w] = cnt;
    __syncthreads();

    int offs = 0;
    for (int ww = 0; ww < w; ++ww) offs += woff[ww];
    const int N = min(woff[0] + woff[1] + woff[2] + woff[3], CAP);

    // ---- Phase 1, pass B: ballot compaction ----
    const unsigned long long lt = (1ull << lane) - 1ull;
    #pragma unroll
    for (int i = 0; i < 8; ++i) {
        int gbase = wbase + i * 256 + lane * 4;
        int h0 = hitp(rv[i].x, btx, bty), h1 = hitp(rv[i].y, btx, bty);
        int h2 = hitp(rv[i].z, btx, bty), h3 = hitp(rv[i].w, btx, bty);
        unsigned long long m0 = __ballot(h0), m1 = __ballot(h1);
        unsigned long long m2 = __ballot(h2), m3 = __ballot(h3);
        int pos = offs + __popcll(m0 & lt) + __popcll(m1 & lt)
                       + __popcll(m2 & lt) + __popcll(m3 & lt);
        if (h0) { if (pos < CAP) slist[pos] = (unsigned short)(gbase    ); pos++; }
        if (h1) { if (pos < CAP) slist[pos] = (unsigned short)(gbase + 1); pos++; }
        if (h2) { if (pos < CAP) slist[pos] = (unsigned short)(gbase + 2); pos++; }
        if (h3) { if (pos < CAP) slist[pos] = (unsigned short)(gbase + 3); pos++; }
        offs += __popcll(m0) + __popcll(m1) + __popcll(m2) + __popcll(m3);
    }
    __syncthreads();

    // ---- Phase 2: rank sort, 32-bit keys + position tiebreak ----
    unsigned short myidx[4]; unsigned int mykey[4]; int myr[4];
    #pragma unroll
    for (int m = 0; m < 4; ++m) {
        int i = t + m * BLK;
        if (i < N) {
            unsigned idx = slist[i];
            unsigned k = __float_as_uint(depths[idx]);   // depths > 0
            myidx[m] = (unsigned short)idx; mykey[m] = k; fkeys[i] = k;
        }
    }
    if (t < 8) fkeys[N + t] = 0xFFFFFFFFu;   // pad: never counts as "<"
    __syncthreads();

    const uint4* fk4 = (const uint4*)fkeys;
    const int nj4 = (N + 3) >> 2;
    #pragma unroll
    for (int m = 0; m < 4; ++m) {
        int i = t + m * BLK;
        if (i < N) {
            unsigned ke = mykey[m]; int r = 0;
            for (int j4 = 0; j4 < nj4; ++j4) {
                uint4 kv = fk4[j4]; int j = j4 << 2;
                r += (int)((kv.x < ke) | ((kv.x == ke) & (j     < i)));
                r += (int)((kv.y < ke) | ((kv.y == ke) & (j + 1 < i)));
                r += (int)((kv.z < ke) | ((kv.z == ke) & (j + 2 < i)));
                r += (int)((kv.w < ke) | ((kv.w == ke) & (j + 3 < i)));
            }
            myr[m] = r;
        }
    }
    __syncthreads();
    #pragma unroll
    for (int m = 0; m < 4; ++m) {
        int i = t + m * BLK;
        if (i < N) slist[myr[m]] = myidx[m];
    }
    __syncthreads();     // sort done; fkeys dead -> sq may overlay it

    // ---- Phase 3: wave w composites depth-chunk w, 4 px/lane ----
    // lane l covers pixels (x = l&15, y = 4*(l>>4) + {0..3})
    const int csz = (N + 3) >> 2;
    const int cs = w * csz;
    const int ce = min(N, cs + csz);

    const float px  = (float)(btx * TILE + (lane & 15)) + 0.5f;
    const int   y0  = (lane >> 4) << 2;
    const float py0 = (float)(bty * TILE + y0) + 0.5f;
    const float py1 = py0 + 1.0f, py2 = py0 + 2.0f, py3 = py0 + 3.0f;

    float T0=1.f,T1=1.f,T2=1.f,T3=1.f;
    float ar0=0.f,ag0=0.f,ab0=0.f, ar1=0.f,ag1=0.f,ab1=0.f;
    float ar2=0.f,ag2=0.f,ab2=0.f, ar3=0.f,ag3=0.f,ab3=0.f;

    for (int base = cs; base < ce; base += BLKB) {
        int k = min(BLKB, ce - base);
        // per-wave staging; pad slots are exact zero-gaussians (op=0)
        float4 v0 = make_float4(0.f,0.f,0.f,0.f);
        float4 v1 = make_float4(0.f,0.f,0.f,0.f);
        float  v2 = 0.f;
        if (lane < k) {
            int idx = slist[base + lane];
            const float4* b = (const float4*)(tbl + (idx << 4));
            v0 = b[0]; v1 = b[1]; v2 = ((const float*)b)[8];
        }
        sq0[w][lane] = v0; sq1[w][lane] = v1; sq2[w][lane] = v2;
        __threadfence_block();         // wave-internal LDS write->read order

        // branchless over the staging round (no exit checks inside)
        int k4 = (k + 3) & ~3;
        #pragma unroll 2
        for (int i = 0; i < k4; i += 4) {
            float4 blv = *(const float4*)&sq2[w][i];   // 4 blues, 1 b128
            #pragma unroll
            for (int u = 0; u < 4; ++u) {
                float4 q0 = sq0[w][i + u];   // ds_read_b128 (broadcast)
                float4 q1 = sq1[w][i + u];   // ds_read_b128 (broadcast)
                float  bl = (u == 0) ? blv.x : (u == 1) ? blv.y
                          : (u == 2) ? blv.z : blv.w;
                float dx = px - q0.x;
                float dxdx = dx * dx;
                float dy0 = py0 - q0.y, dy1 = py1 - q0.y;
                float dy2 = py2 - q0.y, dy3 = py3 - q0.y;
                float sg0 = fmaf(q0.z, dxdx, fmaf(q1.x, dy0*dy0, q0.w*(dx*dy0)));
                float sg1 = fmaf(q0.z, dxdx, fmaf(q1.x, dy1*dy1, q0.w*(dx*dy1)));
                float sg2 = fmaf(q0.z, dxdx, fmaf(q1.x, dy2*dy2, q0.w*(dx*dy2)));
                float sg3 = fmaf(q0.z, dxdx, fmaf(q1.x, dy3*dy3, q0.w*(dx*dy3)));
                float al0 = q1.y * __expf(-sg0);
                float al1 = q1.y * __expf(-sg1);
                float al2 = q1.y * __expf(-sg2);
                float al3 = q1.y * __expf(-sg3);
                al0 = ((sg0 >= 0.f) && (al0 >= ALPHA_THRESH)) ? fminf(al0, ALPHA_CAP) : 0.f;
                al1 = ((sg1 >= 0.f) && (al1 >= ALPHA_THRESH)) ? fminf(al1, ALPHA_CAP) : 0.f;
                al2 = ((sg2 >= 0.f) && (al2 >= ALPHA_THRESH)) ? fminf(al2, ALPHA_CAP) : 0.f;
                al3 = ((sg3 >= 0.f) && (al3 >= ALPHA_THRESH)) ? fminf(al3, ALPHA_CAP) : 0.f;
                float w0 = al0*T0, w1 = al1*T1, w2 = al2*T2, w3 = al3*T3;
                ar0 = fmaf(w0, q1.z, ar0);  ar1 = fmaf(w1, q1.z, ar1);
                ar2 = fmaf(w2, q1.z, ar2);  ar3 = fmaf(w3, q1.z, ar3);
                ag0 = fmaf(w0, q1.w, ag0);  ag1 = fmaf(w1, q1.w, ag1);
                ag2 = fmaf(w2, q1.w, ag2);  ag3 = fmaf(w3, q1.w, ag3);
                ab0 = fmaf(w0, bl,   ab0);  ab1 = fmaf(w1, bl,   ab1);
                ab2 = fmaf(w2, bl,   ab2);  ab3 = fmaf(w3, bl,   ab3);
                T0 *= (1.f - al0);           // matches reference rounding
                T1 *= (1.f - al1);
                T2 *= (1.f - al2);
                T3 *= (1.f - al3);
            }
        }
        // exit check once per staging round (error <= T_cross < 1e-4)
        if (__all((T0 < TRANS_THRESH) & (T1 < TRANS_THRESH) &
                  (T2 < TRANS_THRESH) & (T3 < TRANS_THRESH))) break;
    }

    // ---- Phase 4: barrier (sq dead for ALL waves), then part fold ----
    __syncthreads();                   // sq -> part buffer handoff
    {
        const int xl = lane & 15;
        part[w][(y0    ) * 16 + xl] = make_float4(ar0, ag0, ab0, T0);
        part[w][(y0 + 1) * 16 + xl] = make_float4(ar1, ag1, ab1, T1);
        part[w][(y0 + 2) * 16 + xl] = make_float4(ar2, ag2, ab2, T2);
        part[w][(y0 + 3) * 16 + xl] = make_float4(ar3, ag3, ab3, T3);
    }
    __syncthreads();

    // thread t folds pixel t: C = C0 + T0*(C1 + T1*(C2 + T2*C3))
    float4 p0 = part[0][t], p1 = part[1][t], p2 = part[2][t], p3 = part[3][t];
    float r = p3.x, g = p3.y, b = p3.z;
    r = fmaf(p2.w, r, p2.x); g = fmaf(p2.w, g, p2.y); b = fmaf(p2.w, b, p2.z);
    r = fmaf(p1.w, r, p1.x); g = fmaf(p1.w, g, p1.y); b = fmaf(p1.w, b, p1.z);
    r = fmaf(p0.w, r, p0.x); g = fmaf(p0.w, g, p0.y); b = fmaf(p0.w, b, p0.z);

    const int X = (int)btx * TILE + (t & 15);
    const int Y = (int)bty * TILE + (t >> 4);
    const int o = (Y * IMG_W + X) * 3;
    out[o]     = r;
    out[o + 1] = g;
    out[o + 2] = b;          // BG = 0 -> t_rem term vanishes
}

extern "C" void kernel_launch(void* const* d_in, const int* in_sizes, int n_in,
                              void* d_out, int out_size, void* d_ws, size_t ws_size,
                              hipStream_t stream)
{
    const float* means2d = (const float*)d_in[0];  // (G,2)
    const float* conics  = (const float*)d_in[1];  // (G,3)
    const float* colors  = (const float*)d_in[2];  // (G,3)
    const float* opac    = (const float*)d_in[3];  // (G,)
    const float* depths  = (const float*)d_in[4];  // (G,)
    float* out = (float*)d_out;
    unsigned int* ranges = (unsigned int*)d_ws;                 // 32 KB
    float* tbl = (float*)((char*)d_ws + 32 * 1024);             // G*64 B

    range_kernel<<<G / BLK, BLK, 0, stream>>>(means2d, conics, colors, opac,
                                              ranges, tbl);
    tile_kernel<<<dim3(NTX, NTY), dim3(BLK), 0, stream>>>(
        ranges, depths, tbl, out);
}

// Round 17
// 85.300 us; speedup vs baseline: 2.3780x; 2.3780x over previous
//
#include <hip/hip_runtime.h>

#define G 8192
#define IMG_W 512
#define IMG_H 512
#define TILE 16
#define NTX (IMG_W / TILE)  // 32
#define NTY (IMG_H / TILE)  // 32
#define BLK 256
#define BLKB 64             // per-wave chunk staging group
#define CAP 1024            // per-tile list capacity (avg ~190)
#define ALPHA_THRESH (1.0f/255.0f)
#define ALPHA_CAP 0.99f
#define TRANS_THRESH 1e-4f

// -----------------------------------------------------------------------
// Kernel 0: per-gaussian 16x16-tile span (exact conservative cull,
// packed u32) PLUS a packed 64B record per gaussian:
//   f4[0]=(mx,my,0.5a,b)  f4[1]=(0.5c,op,cr,cg)  f4[2]=(cb,0,0,0)
// -----------------------------------------------------------------------
__global__ __launch_bounds__(BLK)
void range_kernel(const float* __restrict__ means2d,
                  const float* __restrict__ conics,
                  const float* __restrict__ colors,
                  const float* __restrict__ opac,
                  unsigned int* __restrict__ ranges,
                  float* __restrict__ tbl)
{
    int g = blockIdx.x * BLK + threadIdx.x;
    if (g >= G) return;
    float op = opac[g];
    float a  = conics[3*g], b = conics[3*g+1], c = conics[3*g+2];
    float mx = means2d[2*g], my = means2d[2*g+1];
    float cr = colors[3*g], cg = colors[3*g+1], cb = colors[3*g+2];

    float4* t4 = (float4*)(tbl + (g << 4));
    t4[0] = make_float4(mx, my, 0.5f * a, b);
    t4[1] = make_float4(0.5f * c, op, cr, cg);
    t4[2] = make_float4(cb, 0.0f, 0.0f, 0.0f);

    unsigned int packed = 0xFFu;          // default: culled
    if (op * 255.0f >= 1.0f) {
        float smax = __logf(op * 255.0f);
        float det = fmaxf(a * c - b * b, 1e-12f);
        float rx = sqrtf(fmaxf(2.0f * smax * c / det, 0.0f)) * 1.0001f + 0.01f;
        float ry = sqrtf(fmaxf(2.0f * smax * a / det, 0.0f)) * 1.0001f + 0.01f;
        int txmin = (int)ceilf ((mx - rx - 15.5f) * 0.0625f);
        int txmax = (int)floorf((mx + rx -  0.5f) * 0.0625f);
        int tymin = (int)ceilf ((my - ry - 15.5f) * 0.0625f);
        int tymax = (int)floorf((my + ry -  0.5f) * 0.0625f);
        if (!(txmax < 0 || txmin > NTX-1 || tymax < 0 || tymin > NTY-1 ||
              txmin > txmax || tymin > tymax)) {
            txmin = max(txmin, 0); txmax = min(txmax, NTX-1);
            tymin = max(tymin, 0); tymax = min(tymax, NTY-1);
            packed = (unsigned)txmin | ((unsigned)txmax << 8)
                   | ((unsigned)tymin << 16) | ((unsigned)tymax << 24);
        }
    }
    ranges[g] = packed;
}

__device__ __forceinline__ int hitp(unsigned p, unsigned btx, unsigned bty)
{
    return (btx >= (p & 0xffu)) & (btx <= ((p >> 8) & 0xffu)) &
           (bty >= ((p >> 16) & 0xffu)) & (bty <= (p >> 24));
}

// -----------------------------------------------------------------------
// Kernel 1 (one 256-thread block per 16x16 tile; 4 waves) — the 86.6us
// R9 kernel + LDS union (32KB -> 18.9KB: fkeys/sq/part are phase-
// disjoint, one extra barrier at the sq->part handoff). NO launch_bounds
// occupancy arg: R16 showed forcing 8 waves/EU makes the compiler emit
// 32 VGPRs and spill the ~28-reg accumulator state to scratch (FETCH
// 1.7MB -> 180MB, 203us). The kernel's natural demand is ~60 VGPR
// (R13-measured) <= the 64-VGPR hardware occupancy step, so with LDS at
// 18.9KB the HW can reach 8 blocks/CU on its own — soft path to the
// same occupancy doubling.
//  Phase 1: barrier-free two-pass scan + ballot compaction (idx order).
//  Phase 2: rank sort, 32-bit float-bit keys, POSITION tiebreak.
//  Phase 3: chunked composite (wave w = depth-chunk w, 4 px/lane),
//           branchless staging rounds (validated verbatim).
//  Phase 4: in-LDS fold C = C0+T0*(C1+T1*(C2+T2*C3)) (validated).
// -----------------------------------------------------------------------
__global__ __launch_bounds__(BLK)
void tile_kernel(const unsigned int* __restrict__ ranges,
                 const float* __restrict__ depths,
                 const float* __restrict__ tbl,
                 float*       __restrict__ out)
{
    __shared__ __align__(16) unsigned short slist[CAP];   // ph 1-3
    __shared__ int woff[4];
    __shared__ __align__(16) unsigned char ubuf[16384];   // ph-disjoint

    unsigned int* fkeys = (unsigned int*)ubuf;            // ph2: 4128 B
    float4 (*sq0)[BLKB] = (float4 (*)[BLKB])ubuf;         // ph3: 4096 B
    float4 (*sq1)[BLKB] = (float4 (*)[BLKB])(ubuf + 4096);//      4096 B
    float  (*sq2)[BLKB] = (float  (*)[BLKB])(ubuf + 8192);//      1024 B
    float4 (*part)[BLK] = (float4 (*)[BLK])ubuf;          // ph4: 16384 B

    const int t = threadIdx.x;
    const int lane = t & 63, w = t >> 6;
    const unsigned btx = blockIdx.x, bty = blockIdx.y;

    // ---- Phase 1, pass A: load + count (no barriers) ----
    const uint4* r4 = (const uint4*)ranges;
    const int wbase = w * (G / 4);            // 2048 gaussians per wave
    uint4 rv[8];
    #pragma unroll
    for (int i = 0; i < 8; ++i)
        rv[i] = r4[(wbase >> 2) + i * 64 + lane];

    int cnt = 0;
    #pragma unroll
    for (int i = 0; i < 8; ++i)
        cnt += hitp(rv[i].x, btx, bty) + hitp(rv[i].y, btx, bty)
             + hitp(rv[i].z, btx, bty) + hitp(rv[i].w, btx, bty);
    #pragma unroll
    for (int d = 1; d < 64; d <<= 1) cnt += __shfl_xor(cnt, d);
    if (lane == 0) woff[w] = cnt;
    __syncthreads();

    int offs = 0;
    for (int ww = 0; ww < w; ++ww) offs += woff[ww];
    const int N = min(woff[0] + woff[1] + woff[2] + woff[3], CAP);

    // ---- Phase 1, pass B: ballot compaction ----
    const unsigned long long lt = (1ull << lane) - 1ull;
    #pragma unroll
    for (int i = 0; i < 8; ++i) {
        int gbase = wbase + i * 256 + lane * 4;
        int h0 = hitp(rv[i].x, btx, bty), h1 = hitp(rv[i].y, btx, bty);
        int h2 = hitp(rv[i].z, btx, bty), h3 = hitp(rv[i].w, btx, bty);
        unsigned long long m0 = __ballot(h0), m1 = __ballot(h1);
        unsigned long long m2 = __ballot(h2), m3 = __ballot(h3);
        int pos = offs + __popcll(m0 & lt) + __popcll(m1 & lt)
                       + __popcll(m2 & lt) + __popcll(m3 & lt);
        if (h0) { if (pos < CAP) slist[pos] = (unsigned short)(gbase    ); pos++; }
        if (h1) { if (pos < CAP) slist[pos] = (unsigned short)(gbase + 1); pos++; }
        if (h2) { if (pos < CAP) slist[pos] = (unsigned short)(gbase + 2); pos++; }
        if (h3) { if (pos < CAP) slist[pos] = (unsigned short)(gbase + 3); pos++; }
        offs += __popcll(m0) + __popcll(m1) + __popcll(m2) + __popcll(m3);
    }
    __syncthreads();

    // ---- Phase 2: rank sort, 32-bit keys + position tiebreak ----
    unsigned short myidx[4]; unsigned int mykey[4]; int myr[4];
    #pragma unroll
    for (int m = 0; m < 4; ++m) {
        int i = t + m * BLK;
        if (i < N) {
            unsigned idx = slist[i];
            unsigned k = __float_as_uint(depths[idx]);   // depths > 0
            myidx[m] = (unsigned short)idx; mykey[m] = k; fkeys[i] = k;
        }
    }
    if (t < 8) fkeys[N + t] = 0xFFFFFFFFu;   // pad: never counts as "<"
    __syncthreads();

    const uint4* fk4 = (const uint4*)fkeys;
    const int nj4 = (N + 3) >> 2;
    #pragma unroll
    for (int m = 0; m < 4; ++m) {
        int i = t + m * BLK;
        if (i < N) {
            unsigned ke = mykey[m]; int r = 0;
            for (int j4 = 0; j4 < nj4; ++j4) {
                uint4 kv = fk4[j4]; int j = j4 << 2;
                r += (int)((kv.x < ke) | ((kv.x == ke) & (j     < i)));
                r += (int)((kv.y < ke) | ((kv.y == ke) & (j + 1 < i)));
                r += (int)((kv.z < ke) | ((kv.z == ke) & (j + 2 < i)));
                r += (int)((kv.w < ke) | ((kv.w == ke) & (j + 3 < i)));
            }
            myr[m] = r;
        }
    }
    __syncthreads();
    #pragma unroll
    for (int m = 0; m < 4; ++m) {
        int i = t + m * BLK;
        if (i < N) slist[myr[m]] = myidx[m];
    }
    __syncthreads();     // sort done; fkeys dead -> sq may overlay it

    // ---- Phase 3: wave w composites depth-chunk w, 4 px/lane ----
    // lane l covers pixels (x = l&15, y = 4*(l>>4) + {0..3})
    const int csz = (N + 3) >> 2;
    const int cs = w * csz;
    const int ce = min(N, cs + csz);

    const float px  = (float)(btx * TILE + (lane & 15)) + 0.5f;
    const int   y0  = (lane >> 4) << 2;
    const float py0 = (float)(bty * TILE + y0) + 0.5f;
    const float py1 = py0 + 1.0f, py2 = py0 + 2.0f, py3 = py0 + 3.0f;

    float T0=1.f,T1=1.f,T2=1.f,T3=1.f;
    float ar0=0.f,ag0=0.f,ab0=0.f, ar1=0.f,ag1=0.f,ab1=0.f;
    float ar2=0.f,ag2=0.f,ab2=0.f, ar3=0.f,ag3=0.f,ab3=0.f;

    for (int base = cs; base < ce; base += BLKB) {
        int k = min(BLKB, ce - base);
        // per-wave staging; pad slots are exact zero-gaussians (op=0)
        float4 v0 = make_float4(0.f,0.f,0.f,0.f);
        float4 v1 = make_float4(0.f,0.f,0.f,0.f);
        float  v2 = 0.f;
        if (lane < k) {
            int idx = slist[base + lane];
            const float4* b = (const float4*)(tbl + (idx << 4));
            v0 = b[0]; v1 = b[1]; v2 = ((const float*)b)[8];
        }
        sq0[w][lane] = v0; sq1[w][lane] = v1; sq2[w][lane] = v2;
        __threadfence_block();         // wave-internal LDS write->read order

        // branchless over the staging round (no exit checks inside)
        int k4 = (k + 3) & ~3;
        #pragma unroll 2
        for (int i = 0; i < k4; i += 4) {
            float4 blv = *(const float4*)&sq2[w][i];   // 4 blues, 1 b128
            #pragma unroll
            for (int u = 0; u < 4; ++u) {
                float4 q0 = sq0[w][i + u];   // ds_read_b128 (broadcast)
                float4 q1 = sq1[w][i + u];   // ds_read_b128 (broadcast)
                float  bl = (u == 0) ? blv.x : (u == 1) ? blv.y
                          : (u == 2) ? blv.z : blv.w;
                float dx = px - q0.x;
                float dxdx = dx * dx;
                float dy0 = py0 - q0.y, dy1 = py1 - q0.y;
                float dy2 = py2 - q0.y, dy3 = py3 - q0.y;
                float sg0 = fmaf(q0.z, dxdx, fmaf(q1.x, dy0*dy0, q0.w*(dx*dy0)));
                float sg1 = fmaf(q0.z, dxdx, fmaf(q1.x, dy1*dy1, q0.w*(dx*dy1)));
                float sg2 = fmaf(q0.z, dxdx, fmaf(q1.x, dy2*dy2, q0.w*(dx*dy2)));
                float sg3 = fmaf(q0.z, dxdx, fmaf(q1.x, dy3*dy3, q0.w*(dx*dy3)));
                float al0 = q1.y * __expf(-sg0);
                float al1 = q1.y * __expf(-sg1);
                float al2 = q1.y * __expf(-sg2);
                float al3 = q1.y * __expf(-sg3);
                al0 = ((sg0 >= 0.f) && (al0 >= ALPHA_THRESH)) ? fminf(al0, ALPHA_CAP) : 0.f;
                al1 = ((sg1 >= 0.f) && (al1 >= ALPHA_THRESH)) ? fminf(al1, ALPHA_CAP) : 0.f;
                al2 = ((sg2 >= 0.f) && (al2 >= ALPHA_THRESH)) ? fminf(al2, ALPHA_CAP) : 0.f;
                al3 = ((sg3 >= 0.f) && (al3 >= ALPHA_THRESH)) ? fminf(al3, ALPHA_CAP) : 0.f;
                float w0 = al0*T0, w1 = al1*T1, w2 = al2*T2, w3 = al3*T3;
                ar0 = fmaf(w0, q1.z, ar0);  ar1 = fmaf(w1, q1.z, ar1);
                ar2 = fmaf(w2, q1.z, ar2);  ar3 = fmaf(w3, q1.z, ar3);
                ag0 = fmaf(w0, q1.w, ag0);  ag1 = fmaf(w1, q1.w, ag1);
                ag2 = fmaf(w2, q1.w, ag2);  ag3 = fmaf(w3, q1.w, ag3);
                ab0 = fmaf(w0, bl,   ab0);  ab1 = fmaf(w1, bl,   ab1);
                ab2 = fmaf(w2, bl,   ab2);  ab3 = fmaf(w3, bl,   ab3);
                T0 *= (1.f - al0);           // matches reference rounding
                T1 *= (1.f - al1);
                T2 *= (1.f - al2);
                T3 *= (1.f - al3);
            }
        }
        // exit check once per staging round (error <= T_cross < 1e-4)
        if (__all((T0 < TRANS_THRESH) & (T1 < TRANS_THRESH) &
                  (T2 < TRANS_THRESH) & (T3 < TRANS_THRESH))) break;
    }

    // ---- Phase 4: barrier (sq dead for ALL waves), then part fold ----
    __syncthreads();                   // sq -> part buffer handoff
    {
        const int xl = lane & 15;
        part[w][(y0    ) * 16 + xl] = make_float4(ar0, ag0, ab0, T0);
        part[w][(y0 + 1) * 16 + xl] = make_float4(ar1, ag1, ab1, T1);
        part[w][(y0 + 2) * 16 + xl] = make_float4(ar2, ag2, ab2, T2);
        part[w][(y0 + 3) * 16 + xl] = make_float4(ar3, ag3, ab3, T3);
    }
    __syncthreads();

    // thread t folds pixel t: C = C0 + T0*(C1 + T1*(C2 + T2*C3))
    float4 p0 = part[0][t], p1 = part[1][t], p2 = part[2][t], p3 = part[3][t];
    float r = p3.x, g = p3.y, b = p3.z;
    r = fmaf(p2.w, r, p2.x); g = fmaf(p2.w, g, p2.y); b = fmaf(p2.w, b, p2.z);
    r = fmaf(p1.w, r, p1.x); g = fmaf(p1.w, g, p1.y); b = fmaf(p1.w, b, p1.z);
    r = fmaf(p0.w, r, p0.x); g = fmaf(p0.w, g, p0.y); b = fmaf(p0.w, b, p0.z);

    const int X = (int)btx * TILE + (t & 15);
    const int Y = (int)bty * TILE + (t >> 4);
    const int o = (Y * IMG_W + X) * 3;
    out[o]     = r;
    out[o + 1] = g;
    out[o + 2] = b;          // BG = 0 -> t_rem term vanishes
}

extern "C" void kernel_launch(void* const* d_in, const int* in_sizes, int n_in,
                              void* d_out, int out_size, void* d_ws, size_t ws_size,
                              hipStream_t stream)
{
    const float* means2d = (const float*)d_in[0];  // (G,2)
    const float* conics  = (const float*)d_in[1];  // (G,3)
    const float* colors  = (const float*)d_in[2];  // (G,3)
    const float* opac    = (const float*)d_in[3];  // (G,)
    const float* depths  = (const float*)d_in[4];  // (G,)
    float* out = (float*)d_out;
    unsigned int* ranges = (unsigned int*)d_ws;                 // 32 KB
    float* tbl = (float*)((char*)d_ws + 32 * 1024);             // G*64 B

    range_kernel<<<G / BLK, BLK, 0, stream>>>(means2d, conics, colors, opac,
                                              ranges, tbl);
    tile_kernel<<<dim3(NTX, NTY), dim3(BLK), 0, stream>>>(
        ranges, depths, tbl, out);
}